// Round 1
// baseline (1351.460 us; speedup 1.0000x reference)
//
#include <hip/hip_runtime.h>
#include <math.h>

#define NN 20000
#define EE 320000
#define RR 3
#define LL 3
#define HH 4
#define DD 64
#define CDIM 256   // H*D == IN
#define OUTD 128
#define NEG 0.2f

// ---------------- utility kernels ----------------

__global__ void zero_ints(int* p, int n) {
    int i = blockIdx.x * blockDim.x + threadIdx.x;
    if (i < n) p[i] = 0;
}

__global__ void count_deg(const int* __restrict__ edge_dst, int* __restrict__ deg) {
    int i = blockIdx.x * blockDim.x + threadIdx.x;
    if (i >= RR * EE) return;
    int r = i / EE;
    atomicAdd(&deg[r * NN + edge_dst[i]], 1);
}

// one block per relation; chunked Hillis-Steele inclusive scan -> exclusive row_ptr
__global__ void scan_kernel(const int* __restrict__ deg, int* __restrict__ row_ptr) {
    int r = blockIdx.x;
    const int* d = deg + r * NN;
    int* rp = row_ptr + r * (NN + 1);
    __shared__ int buf[1024];
    __shared__ int carry_s;
    if (threadIdx.x == 0) { carry_s = 0; rp[0] = 0; }
    __syncthreads();
    for (int base = 0; base < NN; base += 1024) {
        int i = base + threadIdx.x;
        int v = (i < NN) ? d[i] : 0;
        buf[threadIdx.x] = v;
        __syncthreads();
        for (int off = 1; off < 1024; off <<= 1) {
            int t = (threadIdx.x >= off) ? buf[threadIdx.x - off] : 0;
            __syncthreads();
            buf[threadIdx.x] += t;
            __syncthreads();
        }
        int incl = carry_s + buf[threadIdx.x];
        if (i < NN) rp[i + 1] = incl;
        __syncthreads();
        if (threadIdx.x == 1023) carry_s = carry_s + buf[1023];
        __syncthreads();
    }
}

__global__ void fill_csr(const int* __restrict__ edge_src, const int* __restrict__ edge_dst,
                         const int* __restrict__ row_ptr, int* __restrict__ fill,
                         int* __restrict__ csr_src) {
    int i = blockIdx.x * blockDim.x + threadIdx.x;
    if (i >= RR * EE) return;
    int r = i / EE;
    int dst = edge_dst[i];
    int pos = atomicAdd(&fill[r * NN + dst], 1);
    csr_src[r * EE + row_ptr[r * (NN + 1) + dst] + pos] = edge_src[i];
}

// ---------------- fp32 tiled GEMM: C = A @ B (+bias) ----------------
// BM=BN=64, BK=16, 256 threads, 4x4 microtile. blockIdx.z offsets B and C.

#define BM 64
#define BN 64
#define BK 16

__global__ __launch_bounds__(256) void gemm_k(
    const float* __restrict__ A, const float* __restrict__ B0, float* __restrict__ C0,
    int M, int K, int Ncol, long strideB, long strideC, const float* __restrict__ bias) {
    __shared__ float As[BK][BM + 4];
    __shared__ float Bs[BK][BN];
    const float* B = B0 + (size_t)blockIdx.z * strideB;
    float* C = C0 + (size_t)blockIdx.z * strideC;
    int bm = blockIdx.x * BM, bn = blockIdx.y * BN;
    int t = threadIdx.x;
    int tm = (t >> 4) << 2, tn = (t & 15) << 2;
    float acc[4][4] = {};
    for (int k0 = 0; k0 < K; k0 += BK) {
        {
            int k = t & 15;
            int mrow = t >> 4;
            #pragma unroll
            for (int i = 0; i < 4; i++) {
                int m = mrow + 16 * i;
                int gr = bm + m;
                As[k][m] = (gr < M) ? A[(size_t)gr * K + k0 + k] : 0.f;
            }
        }
        {
            int n = t & 63;
            int kk = t >> 6;
            #pragma unroll
            for (int i = 0; i < 4; i++) {
                int k = kk + 4 * i;
                Bs[k][n] = B[(size_t)(k0 + k) * Ncol + bn + n];
            }
        }
        __syncthreads();
        #pragma unroll
        for (int k = 0; k < BK; k++) {
            float4 a4 = *(const float4*)(&As[k][tm]);
            float4 b4 = *(const float4*)(&Bs[k][tn]);
            float a[4] = {a4.x, a4.y, a4.z, a4.w};
            float b[4] = {b4.x, b4.y, b4.z, b4.w};
            #pragma unroll
            for (int i = 0; i < 4; i++)
                #pragma unroll
                for (int j = 0; j < 4; j++)
                    acc[i][j] = fmaf(a[i], b[j], acc[i][j]);
        }
        __syncthreads();
    }
    #pragma unroll
    for (int i = 0; i < 4; i++) {
        int gr = bm + tm + i;
        if (gr < M) {
            #pragma unroll
            for (int j = 0; j < 4; j++) {
                float v = acc[i][j];
                int gc = bn + tn + j;
                if (bias) v += bias[gc];
                C[(size_t)gr * Ncol + gc] = v;
            }
        }
    }
}

// ---------------- el / er: per-node per-head dot with attn vectors ----------------
// grid (N, R), block 256. wave w handles head w.
__global__ __launch_bounds__(256) void compute_eler(
    const float* __restrict__ feat, const float* __restrict__ al,
    const float* __restrict__ ar, float* __restrict__ el, float* __restrict__ er) {
    int n = blockIdx.x, r = blockIdx.y, c = threadIdx.x;
    int h = c >> 6, lane = c & 63;
    const float* f = feat + ((size_t)r * NN + n) * CDIM;
    float v = f[c];
    float pl = v * al[r * CDIM + c];
    float pr = v * ar[r * CDIM + c];
    #pragma unroll
    for (int off = 32; off; off >>= 1) {
        pl += __shfl_down(pl, off, 64);
        pr += __shfl_down(pr, off, 64);
    }
    if (lane == 0) {
        el[((size_t)r * NN + n) * HH + h] = pl;
        er[((size_t)r * NN + n) * HH + h] = pr;
    }
}

// ---------------- softmax over in-edges: thread per (n,h), blockIdx.y = r --------
__global__ void attn_softmax(const float* __restrict__ el, const float* __restrict__ er,
                             const int* __restrict__ row_ptr, const int* __restrict__ csr_src,
                             float* __restrict__ alpha, float* __restrict__ inv_s) {
    int tid = blockIdx.x * blockDim.x + threadIdx.x;
    int r = blockIdx.y;
    if (tid >= NN * HH) return;
    int n = tid / HH, h = tid - n * HH;
    const int* rp = row_ptr + r * (NN + 1);
    int beg = rp[n], end = rp[n + 1];
    const float* elr = el + (size_t)r * NN * HH;
    float ern = er[((size_t)r * NN + n) * HH + h];
    const int* cs = csr_src + (size_t)r * EE;
    float m = -1e30f;
    for (int e = beg; e < end; e++) {
        int s = cs[e];
        float x = elr[s * HH + h] + ern;
        x = x > 0.f ? x : NEG * x;
        m = fmaxf(m, x);
    }
    float ssum = 0.f;
    float* ar_ = alpha + (size_t)r * EE * HH;
    for (int e = beg; e < end; e++) {
        int s = cs[e];
        float x = elr[s * HH + h] + ern;
        x = x > 0.f ? x : NEG * x;
        float a = __expf(x - m);
        ar_[e * HH + h] = a;
        ssum += a;
    }
    inv_s[((size_t)r * NN + n) * HH + h] = (end > beg) ? 1.f / ssum : 0.f;
}

// ---------------- aggregation: block per dst node, thread per channel ----------
__global__ __launch_bounds__(256) void aggregate(
    const float* __restrict__ feat, const float* __restrict__ alpha,
    const float* __restrict__ inv_s, const int* __restrict__ row_ptr,
    const int* __restrict__ csr_src, const float* __restrict__ bias,
    float* __restrict__ hout, int relu) {
    int n = blockIdx.x, c = threadIdx.x, h = c >> 6;
    float total = 0.f;
    #pragma unroll
    for (int r = 0; r < RR; r++) {
        const int* rp = row_ptr + r * (NN + 1);
        int beg = rp[n], end = rp[n + 1];
        const float* fr = feat + (size_t)r * NN * CDIM;
        const float* ar_ = alpha + (size_t)r * EE * HH;
        const int* cs = csr_src + (size_t)r * EE;
        float part = 0.f;
        for (int e = beg; e < end; e++) {
            int s = cs[e];
            part = fmaf(ar_[e * HH + h], fr[(size_t)s * CDIM + c], part);
        }
        total += part * inv_s[((size_t)r * NN + n) * HH + h] + bias[r * CDIM + c];
    }
    if (relu) total = fmaxf(total, 0.f);
    hout[(size_t)n * CDIM + c] = total;
}

// ---------------- launcher ----------------

extern "C" void kernel_launch(void* const* d_in, const int* in_sizes, int n_in,
                              void* d_out, int out_size, void* d_ws, size_t ws_size,
                              hipStream_t stream) {
    const float* x        = (const float*)d_in[0];
    const int*   edge_src = (const int*)d_in[1];
    const int*   edge_dst = (const int*)d_in[2];
    const float* W        = (const float*)d_in[3];
    const float* attn_l   = (const float*)d_in[4];
    const float* attn_r   = (const float*)d_in[5];
    const float* bias     = (const float*)d_in[6];
    const float* fc_w     = (const float*)d_in[7];
    const float* fc_b     = (const float*)d_in[8];
    float* out = (float*)d_out;

    char* ws = (char*)d_ws;
    size_t off = 0;
    auto alloc = [&](size_t bytes) {
        void* p = ws + off;
        off = (off + bytes + 255) & ~(size_t)255;
        return p;
    };
    float* h_buf  = (float*)alloc((size_t)NN * CDIM * 4);
    float* feat   = (float*)alloc((size_t)RR * NN * CDIM * 4);
    float* el     = (float*)alloc((size_t)RR * NN * HH * 4);
    float* er     = (float*)alloc((size_t)RR * NN * HH * 4);
    float* inv_s  = (float*)alloc((size_t)RR * NN * HH * 4);
    float* alpha  = (float*)alloc((size_t)RR * EE * HH * 4);
    int* row_ptr  = (int*)alloc((size_t)RR * (NN + 1) * 4);
    int* csr_src  = (int*)alloc((size_t)RR * EE * 4);
    int* deg      = (int*)alloc((size_t)2 * RR * NN * 4);
    int* fill     = deg + RR * NN;

    // CSR build (edges shared across layers)
    zero_ints<<<dim3((2 * RR * NN + 1023) / 1024), dim3(1024), 0, stream>>>(deg, 2 * RR * NN);
    count_deg<<<dim3((RR * EE + 255) / 256), dim3(256), 0, stream>>>(edge_dst, deg);
    scan_kernel<<<dim3(RR), dim3(1024), 0, stream>>>(deg, row_ptr);
    fill_csr<<<dim3((RR * EE + 255) / 256), dim3(256), 0, stream>>>(edge_src, edge_dst, row_ptr, fill, csr_src);

    const float* hin = x;
    for (int l = 0; l < LL; l++) {
        const float* Wl = W + (size_t)l * RR * CDIM * CDIM;
        dim3 g((NN + BM - 1) / BM, CDIM / BN, RR);
        gemm_k<<<g, dim3(256), 0, stream>>>(hin, Wl, feat, NN, CDIM, CDIM,
                                            (long)CDIM * CDIM, (long)NN * CDIM, nullptr);
        compute_eler<<<dim3(NN, RR), dim3(256), 0, stream>>>(
            feat, attn_l + (size_t)l * RR * CDIM, attn_r + (size_t)l * RR * CDIM, el, er);
        attn_softmax<<<dim3((NN * HH + 255) / 256, RR), dim3(256), 0, stream>>>(
            el, er, row_ptr, csr_src, alpha, inv_s);
        aggregate<<<dim3(NN), dim3(256), 0, stream>>>(
            feat, alpha, inv_s, row_ptr, csr_src, bias + (size_t)l * RR * CDIM,
            h_buf, (l != LL - 1) ? 1 : 0);
        hin = h_buf;
    }
    dim3 gf((NN + BM - 1) / BM, OUTD / BN, 1);
    gemm_k<<<gf, dim3(256), 0, stream>>>(h_buf, fc_w, out, NN, CDIM, OUTD, 0, 0, fc_b);
}

// Round 2
// 925.472 us; speedup vs baseline: 1.4603x; 1.4603x over previous
//
#include <hip/hip_runtime.h>
#include <math.h>

#define NN 20000
#define EE 320000
#define RR 3
#define LL 3
#define HH 4
#define DD 64
#define CDIM 256   // H*D == IN
#define OUTD 128
#define NEG 0.2f

typedef float f32x4 __attribute__((ext_vector_type(4)));
typedef short sh8 __attribute__((ext_vector_type(8)));

__device__ __forceinline__ ushort f2bf(float f) {
    union { float f; uint u; } v; v.f = f;
    uint r = (v.u + 0x7FFF + ((v.u >> 16) & 1)) >> 16;   // RNE
    return (ushort)r;
}
__device__ __forceinline__ float bf2f(ushort u) {
    union { uint u; float f; } v; v.u = ((uint)u) << 16;
    return v.f;
}

// ---------------- CSR build ----------------

__global__ void zero_ints(int* p, int n) {
    int i = blockIdx.x * blockDim.x + threadIdx.x;
    if (i < n) p[i] = 0;
}

__global__ void count_deg(const int* __restrict__ edge_dst, int* __restrict__ deg) {
    int i = blockIdx.x * blockDim.x + threadIdx.x;
    if (i >= RR * EE) return;
    int r = i / EE;
    atomicAdd(&deg[r * NN + edge_dst[i]], 1);
}

__global__ void scan_kernel(const int* __restrict__ deg, int* __restrict__ row_ptr) {
    int r = blockIdx.x;
    const int* d = deg + r * NN;
    int* rp = row_ptr + r * (NN + 1);
    __shared__ int buf[1024];
    __shared__ int carry_s;
    if (threadIdx.x == 0) { carry_s = 0; rp[0] = 0; }
    __syncthreads();
    for (int base = 0; base < NN; base += 1024) {
        int i = base + threadIdx.x;
        int v = (i < NN) ? d[i] : 0;
        buf[threadIdx.x] = v;
        __syncthreads();
        for (int off = 1; off < 1024; off <<= 1) {
            int t = (threadIdx.x >= off) ? buf[threadIdx.x - off] : 0;
            __syncthreads();
            buf[threadIdx.x] += t;
            __syncthreads();
        }
        int incl = carry_s + buf[threadIdx.x];
        if (i < NN) rp[i + 1] = incl;
        __syncthreads();
        if (threadIdx.x == 1023) carry_s = carry_s + buf[1023];
        __syncthreads();
    }
}

__global__ void fill_csr(const int* __restrict__ edge_src, const int* __restrict__ edge_dst,
                         const int* __restrict__ row_ptr, int* __restrict__ fill,
                         int* __restrict__ csr_src) {
    int i = blockIdx.x * blockDim.x + threadIdx.x;
    if (i >= RR * EE) return;
    int r = i / EE;
    int dst = edge_dst[i];
    int pos = atomicAdd(&fill[r * NN + dst], 1);
    csr_src[r * EE + row_ptr[r * (NN + 1) + dst] + pos] = edge_src[i];
}

// ---------------- dtype prep ----------------

__global__ void cvt_bf16x4(const float* __restrict__ in, ushort* __restrict__ out, int n4) {
    int i = blockIdx.x * blockDim.x + threadIdx.x;
    if (i >= n4) return;
    float4 v = *(const float4*)(in + (size_t)i * 4);
    ushort4 o;
    o.x = f2bf(v.x); o.y = f2bf(v.y); o.z = f2bf(v.z); o.w = f2bf(v.w);
    *(ushort4*)(out + (size_t)i * 4) = o;
}

// transpose [K][N] fp32 -> [N][K] bf16, one matrix per blockIdx.z
__global__ void prep_Wt(const float* __restrict__ W, ushort* __restrict__ Wt, int K, int N) {
    __shared__ float tile[32][33];
    int kb = blockIdx.x * 32, nb = blockIdx.y * 32;
    size_t base = (size_t)blockIdx.z * K * N;
    for (int yy = threadIdx.y; yy < 32; yy += 8)
        tile[yy][threadIdx.x] = W[base + (size_t)(kb + yy) * N + nb + threadIdx.x];
    __syncthreads();
    for (int yy = threadIdx.y; yy < 32; yy += 8)
        Wt[base + (size_t)(nb + yy) * K + kb + threadIdx.x] = f2bf(tile[threadIdx.x][yy]);
}

// ---------------- bf16 MFMA GEMM ----------------
// C[M][Ncol] = A[M][K](bf16) @ Bt[Ncol][K](bf16)^T ; 128x128 tile, BK=32,
// 256 threads = 4 waves, each wave 64x64 via 4x4 grid of 16x16x32 MFMA.

#define TM 128
#define TN 128
#define TK 32
#define LP 40   // LDS row pitch in bf16 elems (80 B: 16B-aligned, breaks 2^k bank stride)

__global__ __launch_bounds__(256) void gemm_bf16(
    const ushort* __restrict__ A, const ushort* __restrict__ Bt0, void* __restrict__ C0,
    int M, int K, int Ncol, long strideB, long strideC,
    const float* __restrict__ bias, int out_fp32) {
    __shared__ alignas(16) ushort As[TM * LP];
    __shared__ alignas(16) ushort Bs[TN * LP];
    const ushort* Bt = Bt0 + (size_t)blockIdx.z * strideB;
    int m0 = blockIdx.x * TM, n0 = blockIdx.y * TN;
    int t = threadIdx.x;
    int wave = t >> 6, lane = t & 63;
    int q = lane >> 4, l16 = lane & 15;
    int wrow = (wave >> 1) * 64, wcol = (wave & 1) * 64;

    f32x4 acc[4][4];
    #pragma unroll
    for (int i = 0; i < 4; i++)
        #pragma unroll
        for (int j = 0; j < 4; j++)
            #pragma unroll
            for (int k = 0; k < 4; k++) acc[i][j][k] = 0.f;

    for (int k0 = 0; k0 < K; k0 += TK) {
        #pragma unroll
        for (int s = 0; s < 2; s++) {
            int qid = t + s * 256;
            int row = qid >> 2, kq = (qid & 3) * 8;
            uint4 v = make_uint4(0, 0, 0, 0);
            int gr = m0 + row;
            if (gr < M) v = *(const uint4*)(A + (size_t)gr * K + k0 + kq);
            *(uint4*)(As + row * LP + kq) = v;
        }
        #pragma unroll
        for (int s = 0; s < 2; s++) {
            int qid = t + s * 256;
            int row = qid >> 2, kq = (qid & 3) * 8;
            uint4 v = *(const uint4*)(Bt + (size_t)(n0 + row) * K + k0 + kq);
            *(uint4*)(Bs + row * LP + kq) = v;
        }
        __syncthreads();
        sh8 af[4], bfr[4];
        #pragma unroll
        for (int i = 0; i < 4; i++)
            af[i] = *(const sh8*)(As + (wrow + i * 16 + l16) * LP + q * 8);
        #pragma unroll
        for (int j = 0; j < 4; j++)
            bfr[j] = *(const sh8*)(Bs + (wcol + j * 16 + l16) * LP + q * 8);
        #pragma unroll
        for (int i = 0; i < 4; i++)
            #pragma unroll
            for (int j = 0; j < 4; j++)
                acc[i][j] = __builtin_amdgcn_mfma_f32_16x16x32_bf16(af[i], bfr[j], acc[i][j], 0, 0, 0);
        __syncthreads();
    }

    // epilogue: C/D layout col=lane&15, row=q*4+reg
    if (out_fp32) {
        float* C = (float*)C0 + (size_t)blockIdx.z * strideC;
        #pragma unroll
        for (int i = 0; i < 4; i++) {
            #pragma unroll
            for (int reg = 0; reg < 4; reg++) {
                int row = m0 + wrow + i * 16 + q * 4 + reg;
                if (row >= M) continue;
                #pragma unroll
                for (int j = 0; j < 4; j++) {
                    int col = n0 + wcol + j * 16 + l16;
                    float v = acc[i][j][reg];
                    if (bias) v += bias[col];
                    C[(size_t)row * Ncol + col] = v;
                }
            }
        }
    } else {
        ushort* C = (ushort*)C0 + (size_t)blockIdx.z * strideC;
        #pragma unroll
        for (int i = 0; i < 4; i++) {
            #pragma unroll
            for (int reg = 0; reg < 4; reg++) {
                int row = m0 + wrow + i * 16 + q * 4 + reg;
                if (row >= M) continue;
                #pragma unroll
                for (int j = 0; j < 4; j++) {
                    int col = n0 + wcol + j * 16 + l16;
                    C[(size_t)row * Ncol + col] = f2bf(acc[i][j][reg]);
                }
            }
        }
    }
}

// ---------------- el / er ----------------
// wave per node; lane reads 4 channels (8 B); reduce within 16-lane head groups.
__global__ __launch_bounds__(256) void compute_eler(
    const ushort* __restrict__ feat16, const float* __restrict__ al,
    const float* __restrict__ ar, float* __restrict__ el, float* __restrict__ er) {
    int wave = threadIdx.x >> 6, lane = threadIdx.x & 63;
    int n = blockIdx.x * 4 + wave;
    if (n >= NN) return;
    int h = lane >> 4;
    int c = lane * 4;
    for (int r = 0; r < RR; r++) {
        const ushort* f = feat16 + ((size_t)r * NN + n) * CDIM + c;
        uint2 p = *(const uint2*)f;
        float fv[4];
        fv[0] = bf2f((ushort)(p.x & 0xffff));
        fv[1] = bf2f((ushort)(p.x >> 16));
        fv[2] = bf2f((ushort)(p.y & 0xffff));
        fv[3] = bf2f((ushort)(p.y >> 16));
        float pl = 0.f, pr = 0.f;
        #pragma unroll
        for (int i = 0; i < 4; i++) {
            pl = fmaf(fv[i], al[r * CDIM + c + i], pl);
            pr = fmaf(fv[i], ar[r * CDIM + c + i], pr);
        }
        #pragma unroll
        for (int m = 1; m < 16; m <<= 1) {
            pl += __shfl_xor(pl, m, 64);
            pr += __shfl_xor(pr, m, 64);
        }
        if ((lane & 15) == 0) {
            el[((size_t)r * NN + n) * HH + h] = pl;
            er[((size_t)r * NN + n) * HH + h] = pr;
        }
    }
}

// ---------------- softmax over in-edges ----------------
__global__ void attn_softmax(const float* __restrict__ el, const float* __restrict__ er,
                             const int* __restrict__ row_ptr, const int* __restrict__ csr_src,
                             float* __restrict__ alpha, float* __restrict__ inv_s) {
    int tid = blockIdx.x * blockDim.x + threadIdx.x;
    int r = blockIdx.y;
    if (tid >= NN * HH) return;
    int n = tid / HH, h = tid - n * HH;
    const int* rp = row_ptr + r * (NN + 1);
    int beg = rp[n], end = rp[n + 1];
    const float* elr = el + (size_t)r * NN * HH;
    float ern = er[((size_t)r * NN + n) * HH + h];
    const int* cs = csr_src + (size_t)r * EE;
    float m = -1e30f;
    for (int e = beg; e < end; e++) {
        int s = cs[e];
        float x = elr[s * HH + h] + ern;
        x = x > 0.f ? x : NEG * x;
        m = fmaxf(m, x);
    }
    float ssum = 0.f;
    float* ar_ = alpha + (size_t)r * EE * HH;
    for (int e = beg; e < end; e++) {
        int s = cs[e];
        float x = elr[s * HH + h] + ern;
        x = x > 0.f ? x : NEG * x;
        float a = __expf(x - m);
        ar_[e * HH + h] = a;
        ssum += a;
    }
    inv_s[((size_t)r * NN + n) * HH + h] = (end > beg) ? 1.f / ssum : 0.f;
}

// ---------------- aggregation ----------------
// 2 nodes per 256-thread block; 128 threads per node, 2 channels each (bf16x2 gather).
__global__ __launch_bounds__(256) void aggregate(
    const ushort* __restrict__ feat16, const float* __restrict__ alpha,
    const float* __restrict__ inv_s, const int* __restrict__ row_ptr,
    const int* __restrict__ csr_src, const float* __restrict__ bias,
    ushort* __restrict__ hout, int relu) {
    int node = blockIdx.x * 2 + (threadIdx.x >> 7);
    int t = threadIdx.x & 127;
    int c0 = t * 2;
    int h = c0 >> 6;
    float t0 = 0.f, t1 = 0.f;
    #pragma unroll
    for (int r = 0; r < RR; r++) {
        const int* rp = row_ptr + r * (NN + 1);
        int beg = rp[node], end = rp[node + 1];
        const ushort* fr = feat16 + (size_t)r * NN * CDIM;
        const float* ar_ = alpha + (size_t)r * EE * HH;
        const int* cs = csr_src + (size_t)r * EE;
        float p0 = 0.f, p1 = 0.f;
        for (int e = beg; e < end; e++) {
            int s = cs[e];
            float a = ar_[e * HH + h];
            uint p = *(const uint*)(fr + (size_t)s * CDIM + c0);
            p0 = fmaf(a, bf2f((ushort)(p & 0xffff)), p0);
            p1 = fmaf(a, bf2f((ushort)(p >> 16)), p1);
        }
        float is = inv_s[((size_t)r * NN + node) * HH + h];
        t0 += p0 * is + bias[r * CDIM + c0];
        t1 += p1 * is + bias[r * CDIM + c0 + 1];
    }
    if (relu) { t0 = fmaxf(t0, 0.f); t1 = fmaxf(t1, 0.f); }
    uint packed = (uint)f2bf(t0) | ((uint)f2bf(t1) << 16);
    *(uint*)(hout + (size_t)node * CDIM + c0) = packed;
}

// ---------------- launcher ----------------

extern "C" void kernel_launch(void* const* d_in, const int* in_sizes, int n_in,
                              void* d_out, int out_size, void* d_ws, size_t ws_size,
                              hipStream_t stream) {
    const float* x        = (const float*)d_in[0];
    const int*   edge_src = (const int*)d_in[1];
    const int*   edge_dst = (const int*)d_in[2];
    const float* W        = (const float*)d_in[3];
    const float* attn_l   = (const float*)d_in[4];
    const float* attn_r   = (const float*)d_in[5];
    const float* bias     = (const float*)d_in[6];
    const float* fc_w     = (const float*)d_in[7];
    const float* fc_b     = (const float*)d_in[8];
    float* out = (float*)d_out;

    char* ws = (char*)d_ws;
    size_t off = 0;
    auto alloc = [&](size_t bytes) {
        void* p = ws + off;
        off = (off + bytes + 255) & ~(size_t)255;
        return p;
    };
    ushort* x16    = (ushort*)alloc((size_t)NN * CDIM * 2);
    ushort* h16    = (ushort*)alloc((size_t)NN * CDIM * 2);
    ushort* feat16 = (ushort*)alloc((size_t)RR * NN * CDIM * 2);
    ushort* Wt16   = (ushort*)alloc((size_t)LL * RR * CDIM * CDIM * 2);
    ushort* fct16  = (ushort*)alloc((size_t)OUTD * CDIM * 2);
    float* el      = (float*)alloc((size_t)RR * NN * HH * 4);
    float* er      = (float*)alloc((size_t)RR * NN * HH * 4);
    float* inv_s   = (float*)alloc((size_t)RR * NN * HH * 4);
    float* alpha   = (float*)alloc((size_t)RR * EE * HH * 4);
    int* row_ptr   = (int*)alloc((size_t)RR * (NN + 1) * 4);
    int* csr_src   = (int*)alloc((size_t)RR * EE * 4);
    int* deg       = (int*)alloc((size_t)2 * RR * NN * 4);
    int* fill      = deg + RR * NN;

    // CSR build
    zero_ints<<<dim3((2 * RR * NN + 1023) / 1024), dim3(1024), 0, stream>>>(deg, 2 * RR * NN);
    count_deg<<<dim3((RR * EE + 255) / 256), dim3(256), 0, stream>>>(edge_dst, deg);
    scan_kernel<<<dim3(RR), dim3(1024), 0, stream>>>(deg, row_ptr);
    fill_csr<<<dim3((RR * EE + 255) / 256), dim3(256), 0, stream>>>(edge_src, edge_dst, row_ptr, fill, csr_src);

    // dtype prep
    cvt_bf16x4<<<dim3((NN * CDIM / 4 + 255) / 256), dim3(256), 0, stream>>>(x, x16, NN * CDIM / 4);
    prep_Wt<<<dim3(CDIM / 32, CDIM / 32, LL * RR), dim3(32, 8), 0, stream>>>(W, Wt16, CDIM, CDIM);
    prep_Wt<<<dim3(CDIM / 32, OUTD / 32, 1), dim3(32, 8), 0, stream>>>(fc_w, fct16, CDIM, OUTD);

    const ushort* hin = x16;
    for (int l = 0; l < LL; l++) {
        const ushort* Wl = Wt16 + (size_t)l * RR * CDIM * CDIM;
        dim3 g((NN + TM - 1) / TM, CDIM / TN, RR);
        gemm_bf16<<<g, dim3(256), 0, stream>>>(hin, Wl, feat16, NN, CDIM, CDIM,
                                               (long)CDIM * CDIM, (long)NN * CDIM, nullptr, 0);
        compute_eler<<<dim3(NN / 4), dim3(256), 0, stream>>>(
            feat16, attn_l + (size_t)l * RR * CDIM, attn_r + (size_t)l * RR * CDIM, el, er);
        attn_softmax<<<dim3((NN * HH + 255) / 256, RR), dim3(256), 0, stream>>>(
            el, er, row_ptr, csr_src, alpha, inv_s);
        aggregate<<<dim3(NN / 2), dim3(256), 0, stream>>>(
            feat16, alpha, inv_s, row_ptr, csr_src, bias + (size_t)l * RR * CDIM,
            h16, (l != LL - 1) ? 1 : 0);
        hin = h16;
    }
    dim3 gf((NN + TM - 1) / TM, OUTD / TN, 1);
    gemm_bf16<<<gf, dim3(256), 0, stream>>>(h16, fct16, out, NN, CDIM, OUTD,
                                            0, 0, fc_b, 1);
}

// Round 3
// 590.503 us; speedup vs baseline: 2.2887x; 1.5673x over previous
//
#include <hip/hip_runtime.h>
#include <math.h>

#define NN 20000
#define EE 320000
#define RR 3
#define LL 3
#define HH 4
#define DD 64
#define CDIM 256   // H*D == IN
#define OUTD 128
#define NEG 0.2f

typedef float f32x4 __attribute__((ext_vector_type(4)));
typedef short sh8 __attribute__((ext_vector_type(8)));

__device__ __forceinline__ ushort f2bf(float f) {
    union { float f; uint u; } v; v.f = f;
    uint r = (v.u + 0x7FFF + ((v.u >> 16) & 1)) >> 16;   // RNE
    return (ushort)r;
}
__device__ __forceinline__ float bf2f(ushort u) {
    union { uint u; float f; } v; v.u = ((uint)u) << 16;
    return v.f;
}
__device__ __forceinline__ float bflo(uint p) { return bf2f((ushort)(p & 0xffff)); }
__device__ __forceinline__ float bfhi(uint p) { return bf2f((ushort)(p >> 16)); }

// ---------------- CSR build ----------------

__global__ void zero_ints(int* p, int n) {
    int i = blockIdx.x * blockDim.x + threadIdx.x;
    if (i < n) p[i] = 0;
}

__global__ void count_deg(const int* __restrict__ edge_dst, int* __restrict__ deg) {
    int i = blockIdx.x * blockDim.x + threadIdx.x;
    if (i >= RR * EE) return;
    int r = i / EE;
    atomicAdd(&deg[r * NN + edge_dst[i]], 1);
}

__global__ void scan_kernel(const int* __restrict__ deg, int* __restrict__ row_ptr) {
    int r = blockIdx.x;
    const int* d = deg + r * NN;
    int* rp = row_ptr + r * (NN + 1);
    __shared__ int buf[1024];
    __shared__ int carry_s;
    if (threadIdx.x == 0) { carry_s = 0; rp[0] = 0; }
    __syncthreads();
    for (int base = 0; base < NN; base += 1024) {
        int i = base + threadIdx.x;
        int v = (i < NN) ? d[i] : 0;
        buf[threadIdx.x] = v;
        __syncthreads();
        for (int off = 1; off < 1024; off <<= 1) {
            int t = (threadIdx.x >= off) ? buf[threadIdx.x - off] : 0;
            __syncthreads();
            buf[threadIdx.x] += t;
            __syncthreads();
        }
        int incl = carry_s + buf[threadIdx.x];
        if (i < NN) rp[i + 1] = incl;
        __syncthreads();
        if (threadIdx.x == 1023) carry_s = carry_s + buf[1023];
        __syncthreads();
    }
}

__global__ void fill_csr(const int* __restrict__ edge_src, const int* __restrict__ edge_dst,
                         const int* __restrict__ row_ptr, int* __restrict__ fill,
                         int* __restrict__ csr_src) {
    int i = blockIdx.x * blockDim.x + threadIdx.x;
    if (i >= RR * EE) return;
    int r = i / EE;
    int dst = edge_dst[i];
    int pos = atomicAdd(&fill[r * NN + dst], 1);
    csr_src[r * EE + row_ptr[r * (NN + 1) + dst] + pos] = edge_src[i];
}

// ---------------- dtype prep ----------------

__global__ void cvt_bf16x4(const float* __restrict__ in, ushort* __restrict__ out, int n4) {
    int i = blockIdx.x * blockDim.x + threadIdx.x;
    if (i >= n4) return;
    float4 v = *(const float4*)(in + (size_t)i * 4);
    ushort4 o;
    o.x = f2bf(v.x); o.y = f2bf(v.y); o.z = f2bf(v.z); o.w = f2bf(v.w);
    *(ushort4*)(out + (size_t)i * 4) = o;
}

// transpose [K][N] fp32 -> [N][K] bf16, one matrix per blockIdx.z
__global__ void prep_Wt(const float* __restrict__ W, ushort* __restrict__ Wt, int K, int N) {
    __shared__ float tile[32][33];
    int kb = blockIdx.x * 32, nb = blockIdx.y * 32;
    size_t base = (size_t)blockIdx.z * K * N;
    for (int yy = threadIdx.y; yy < 32; yy += 8)
        tile[yy][threadIdx.x] = W[base + (size_t)(kb + yy) * N + nb + threadIdx.x];
    __syncthreads();
    for (int yy = threadIdx.y; yy < 32; yy += 8)
        Wt[base + (size_t)(nb + yy) * K + kb + threadIdx.x] = f2bf(tile[threadIdx.x][yy]);
}

// ---------------- bf16 MFMA GEMM ----------------
// C[M][Ncol] = A[M][K](bf16) @ Bt[Ncol][K](bf16)^T ; 128x128 tile, BK=32,
// 256 threads = 4 waves, each wave 64x64 via 4x4 grid of 16x16x32 MFMA.

#define TM 128
#define TN 128
#define TK 32
#define LP 40   // LDS row pitch in bf16 elems (80 B: 16B-aligned, breaks 2^k bank stride)

__global__ __launch_bounds__(256) void gemm_bf16(
    const ushort* __restrict__ A, const ushort* __restrict__ Bt0, void* __restrict__ C0,
    int M, int K, int Ncol, long strideB, long strideC,
    const float* __restrict__ bias, int out_fp32) {
    __shared__ alignas(16) ushort As[TM * LP];
    __shared__ alignas(16) ushort Bs[TN * LP];
    const ushort* Bt = Bt0 + (size_t)blockIdx.z * strideB;
    int m0 = blockIdx.x * TM, n0 = blockIdx.y * TN;
    int t = threadIdx.x;
    int wave = t >> 6, lane = t & 63;
    int q = lane >> 4, l16 = lane & 15;
    int wrow = (wave >> 1) * 64, wcol = (wave & 1) * 64;

    f32x4 acc[4][4];
    #pragma unroll
    for (int i = 0; i < 4; i++)
        #pragma unroll
        for (int j = 0; j < 4; j++)
            #pragma unroll
            for (int k = 0; k < 4; k++) acc[i][j][k] = 0.f;

    for (int k0 = 0; k0 < K; k0 += TK) {
        #pragma unroll
        for (int s = 0; s < 2; s++) {
            int qid = t + s * 256;
            int row = qid >> 2, kq = (qid & 3) * 8;
            uint4 v = make_uint4(0, 0, 0, 0);
            int gr = m0 + row;
            if (gr < M) v = *(const uint4*)(A + (size_t)gr * K + k0 + kq);
            *(uint4*)(As + row * LP + kq) = v;
        }
        #pragma unroll
        for (int s = 0; s < 2; s++) {
            int qid = t + s * 256;
            int row = qid >> 2, kq = (qid & 3) * 8;
            uint4 v = *(const uint4*)(Bt + (size_t)(n0 + row) * K + k0 + kq);
            *(uint4*)(Bs + row * LP + kq) = v;
        }
        __syncthreads();
        sh8 af[4], bfr[4];
        #pragma unroll
        for (int i = 0; i < 4; i++)
            af[i] = *(const sh8*)(As + (wrow + i * 16 + l16) * LP + q * 8);
        #pragma unroll
        for (int j = 0; j < 4; j++)
            bfr[j] = *(const sh8*)(Bs + (wcol + j * 16 + l16) * LP + q * 8);
        #pragma unroll
        for (int i = 0; i < 4; i++)
            #pragma unroll
            for (int j = 0; j < 4; j++)
                acc[i][j] = __builtin_amdgcn_mfma_f32_16x16x32_bf16(af[i], bfr[j], acc[i][j], 0, 0, 0);
        __syncthreads();
    }

    // epilogue: C/D layout col=lane&15, row=q*4+reg
    if (out_fp32) {
        float* C = (float*)C0 + (size_t)blockIdx.z * strideC;
        #pragma unroll
        for (int i = 0; i < 4; i++) {
            #pragma unroll
            for (int reg = 0; reg < 4; reg++) {
                int row = m0 + wrow + i * 16 + q * 4 + reg;
                if (row >= M) continue;
                #pragma unroll
                for (int j = 0; j < 4; j++) {
                    int col = n0 + wcol + j * 16 + l16;
                    float v = acc[i][j][reg];
                    if (bias) v += bias[col];
                    C[(size_t)row * Ncol + col] = v;
                }
            }
        }
    } else {
        ushort* C = (ushort*)C0 + (size_t)blockIdx.z * strideC;
        #pragma unroll
        for (int i = 0; i < 4; i++) {
            #pragma unroll
            for (int reg = 0; reg < 4; reg++) {
                int row = m0 + wrow + i * 16 + q * 4 + reg;
                if (row >= M) continue;
                #pragma unroll
                for (int j = 0; j < 4; j++) {
                    int col = n0 + wcol + j * 16 + l16;
                    C[(size_t)row * Ncol + col] = f2bf(acc[i][j][reg]);
                }
            }
        }
    }
}

// ---------------- el / er ----------------
// wave per node; lane reads 4 channels (8 B); reduce within 16-lane head groups.
__global__ __launch_bounds__(256) void compute_eler(
    const ushort* __restrict__ feat16, const float* __restrict__ al,
    const float* __restrict__ ar, float* __restrict__ el, float* __restrict__ er) {
    int wave = threadIdx.x >> 6, lane = threadIdx.x & 63;
    int n = blockIdx.x * 4 + wave;
    if (n >= NN) return;
    int h = lane >> 4;
    int c = lane * 4;
    for (int r = 0; r < RR; r++) {
        const ushort* f = feat16 + ((size_t)r * NN + n) * CDIM + c;
        uint2 p = *(const uint2*)f;
        float fv[4];
        fv[0] = bflo(p.x); fv[1] = bfhi(p.x); fv[2] = bflo(p.y); fv[3] = bfhi(p.y);
        float pl = 0.f, pr = 0.f;
        #pragma unroll
        for (int i = 0; i < 4; i++) {
            pl = fmaf(fv[i], al[r * CDIM + c + i], pl);
            pr = fmaf(fv[i], ar[r * CDIM + c + i], pr);
        }
        #pragma unroll
        for (int m = 1; m < 16; m <<= 1) {
            pl += __shfl_xor(pl, m, 64);
            pr += __shfl_xor(pr, m, 64);
        }
        if ((lane & 15) == 0) {
            el[((size_t)r * NN + n) * HH + h] = pl;
            er[((size_t)r * NN + n) * HH + h] = pr;
        }
    }
}

// ---------------- softmax over in-edges ----------------
// wave per (node, r): lane = (edge_local<<2)|head -> 16 edges x 4 heads per pass.
// Max-subtraction dropped: |x| <~ 40 << 88, expf cannot overflow; alpha/s ratio
// is algebraically identical to the reference's exp(x-m)/sum(exp(x-m)).
__global__ __launch_bounds__(256) void attn_softmax(
    const float* __restrict__ el, const float* __restrict__ er,
    const int* __restrict__ row_ptr, const int* __restrict__ csr_src,
    float* __restrict__ alpha, float* __restrict__ inv_s) {
    int wv = threadIdx.x >> 6, lane = threadIdx.x & 63;
    int n = blockIdx.x * 4 + wv;
    int r = blockIdx.y;
    if (n >= NN) return;
    const int* rp = row_ptr + r * (NN + 1);
    int beg = rp[n], end = rp[n + 1];
    int h = lane & 3, eo = lane >> 2;
    float ern = er[((size_t)r * NN + n) * HH + h];
    const float* elr = el + (size_t)r * NN * HH;
    float* ar_ = alpha + (size_t)r * EE * HH;
    const int* cs = csr_src + (size_t)r * EE;
    float ssum = 0.f;
    for (int e0 = beg; e0 < end; e0 += 16) {
        int e = e0 + eo;
        float a = 0.f;
        if (e < end) {
            int s = cs[e];
            float x = elr[s * HH + h] + ern;
            x = x > 0.f ? x : NEG * x;
            a = __expf(x);
            ar_[e * HH + h] = a;
        }
        ssum += a;
    }
    ssum += __shfl_xor(ssum, 4, 64);
    ssum += __shfl_xor(ssum, 8, 64);
    ssum += __shfl_xor(ssum, 16, 64);
    ssum += __shfl_xor(ssum, 32, 64);
    if (lane < 4) inv_s[((size_t)r * NN + n) * HH + lane] = (ssum > 0.f) ? 1.f / ssum : 0.f;
}

// ---------------- aggregation ----------------
// wave per node (4 nodes / block); lane owns 4 channels (one uint2 = 8 B);
// 4-edge software pipeline: all 4 gathers issued before their FMAs.
__global__ __launch_bounds__(256) void aggregate(
    const ushort* __restrict__ feat16, const float* __restrict__ alpha,
    const float* __restrict__ inv_s, const int* __restrict__ row_ptr,
    const int* __restrict__ csr_src, const float* __restrict__ bias,
    ushort* __restrict__ hout, int relu) {
    int wv = threadIdx.x >> 6, lane = threadIdx.x & 63;
    int node = blockIdx.x * 4 + wv;
    if (node >= NN) return;
    int c0 = lane * 4;
    int h = lane >> 4;
    float t0 = 0.f, t1 = 0.f, t2 = 0.f, t3 = 0.f;
    #pragma unroll
    for (int r = 0; r < RR; r++) {
        const int* rp = row_ptr + r * (NN + 1);
        int beg = rp[node], end = rp[node + 1];
        const ushort* fr = feat16 + (size_t)r * NN * CDIM;
        const float* ar_ = alpha + (size_t)r * EE * HH;
        const int* cs = csr_src + (size_t)r * EE;
        float p0 = 0.f, p1 = 0.f, p2 = 0.f, p3 = 0.f;
        int e = beg;
        for (; e + 4 <= end; e += 4) {
            int s0 = cs[e], s1 = cs[e + 1], s2 = cs[e + 2], s3 = cs[e + 3];
            float w0 = ar_[(e + 0) * HH + h];
            float w1 = ar_[(e + 1) * HH + h];
            float w2 = ar_[(e + 2) * HH + h];
            float w3 = ar_[(e + 3) * HH + h];
            uint2 f0 = *(const uint2*)(fr + (size_t)s0 * CDIM + c0);
            uint2 f1 = *(const uint2*)(fr + (size_t)s1 * CDIM + c0);
            uint2 f2 = *(const uint2*)(fr + (size_t)s2 * CDIM + c0);
            uint2 f3 = *(const uint2*)(fr + (size_t)s3 * CDIM + c0);
            p0 = fmaf(w0, bflo(f0.x), p0); p1 = fmaf(w0, bfhi(f0.x), p1);
            p2 = fmaf(w0, bflo(f0.y), p2); p3 = fmaf(w0, bfhi(f0.y), p3);
            p0 = fmaf(w1, bflo(f1.x), p0); p1 = fmaf(w1, bfhi(f1.x), p1);
            p2 = fmaf(w1, bflo(f1.y), p2); p3 = fmaf(w1, bfhi(f1.y), p3);
            p0 = fmaf(w2, bflo(f2.x), p0); p1 = fmaf(w2, bfhi(f2.x), p1);
            p2 = fmaf(w2, bflo(f2.y), p2); p3 = fmaf(w2, bfhi(f2.y), p3);
            p0 = fmaf(w3, bflo(f3.x), p0); p1 = fmaf(w3, bfhi(f3.x), p1);
            p2 = fmaf(w3, bflo(f3.y), p2); p3 = fmaf(w3, bfhi(f3.y), p3);
        }
        for (; e < end; e++) {
            int s = cs[e];
            float w = ar_[e * HH + h];
            uint2 f = *(const uint2*)(fr + (size_t)s * CDIM + c0);
            p0 = fmaf(w, bflo(f.x), p0); p1 = fmaf(w, bfhi(f.x), p1);
            p2 = fmaf(w, bflo(f.y), p2); p3 = fmaf(w, bfhi(f.y), p3);
        }
        float is = inv_s[((size_t)r * NN + node) * HH + h];
        t0 += p0 * is + bias[r * CDIM + c0];
        t1 += p1 * is + bias[r * CDIM + c0 + 1];
        t2 += p2 * is + bias[r * CDIM + c0 + 2];
        t3 += p3 * is + bias[r * CDIM + c0 + 3];
    }
    if (relu) {
        t0 = fmaxf(t0, 0.f); t1 = fmaxf(t1, 0.f);
        t2 = fmaxf(t2, 0.f); t3 = fmaxf(t3, 0.f);
    }
    uint2 o;
    o.x = (uint)f2bf(t0) | ((uint)f2bf(t1) << 16);
    o.y = (uint)f2bf(t2) | ((uint)f2bf(t3) << 16);
    *(uint2*)(hout + (size_t)node * CDIM + c0) = o;
}

// ---------------- launcher ----------------

extern "C" void kernel_launch(void* const* d_in, const int* in_sizes, int n_in,
                              void* d_out, int out_size, void* d_ws, size_t ws_size,
                              hipStream_t stream) {
    const float* x        = (const float*)d_in[0];
    const int*   edge_src = (const int*)d_in[1];
    const int*   edge_dst = (const int*)d_in[2];
    const float* W        = (const float*)d_in[3];
    const float* attn_l   = (const float*)d_in[4];
    const float* attn_r   = (const float*)d_in[5];
    const float* bias     = (const float*)d_in[6];
    const float* fc_w     = (const float*)d_in[7];
    const float* fc_b     = (const float*)d_in[8];
    float* out = (float*)d_out;

    char* ws = (char*)d_ws;
    size_t off = 0;
    auto alloc = [&](size_t bytes) {
        void* p = ws + off;
        off = (off + bytes + 255) & ~(size_t)255;
        return p;
    };
    ushort* x16    = (ushort*)alloc((size_t)NN * CDIM * 2);
    ushort* h16    = (ushort*)alloc((size_t)NN * CDIM * 2);
    ushort* feat16 = (ushort*)alloc((size_t)RR * NN * CDIM * 2);
    ushort* Wt16   = (ushort*)alloc((size_t)LL * RR * CDIM * CDIM * 2);
    ushort* fct16  = (ushort*)alloc((size_t)OUTD * CDIM * 2);
    float* el      = (float*)alloc((size_t)RR * NN * HH * 4);
    float* er      = (float*)alloc((size_t)RR * NN * HH * 4);
    float* inv_s   = (float*)alloc((size_t)RR * NN * HH * 4);
    float* alpha   = (float*)alloc((size_t)RR * EE * HH * 4);
    int* row_ptr   = (int*)alloc((size_t)RR * (NN + 1) * 4);
    int* csr_src   = (int*)alloc((size_t)RR * EE * 4);
    int* deg       = (int*)alloc((size_t)2 * RR * NN * 4);
    int* fill      = deg + RR * NN;

    // CSR build
    zero_ints<<<dim3((2 * RR * NN + 1023) / 1024), dim3(1024), 0, stream>>>(deg, 2 * RR * NN);
    count_deg<<<dim3((RR * EE + 255) / 256), dim3(256), 0, stream>>>(edge_dst, deg);
    scan_kernel<<<dim3(RR), dim3(1024), 0, stream>>>(deg, row_ptr);
    fill_csr<<<dim3((RR * EE + 255) / 256), dim3(256), 0, stream>>>(edge_src, edge_dst, row_ptr, fill, csr_src);

    // dtype prep
    cvt_bf16x4<<<dim3((NN * CDIM / 4 + 255) / 256), dim3(256), 0, stream>>>(x, x16, NN * CDIM / 4);
    prep_Wt<<<dim3(CDIM / 32, CDIM / 32, LL * RR), dim3(32, 8), 0, stream>>>(W, Wt16, CDIM, CDIM);
    prep_Wt<<<dim3(CDIM / 32, OUTD / 32, 1), dim3(32, 8), 0, stream>>>(fc_w, fct16, CDIM, OUTD);

    const ushort* hin = x16;
    for (int l = 0; l < LL; l++) {
        const ushort* Wl = Wt16 + (size_t)l * RR * CDIM * CDIM;
        dim3 g((NN + TM - 1) / TM, CDIM / TN, RR);
        gemm_bf16<<<g, dim3(256), 0, stream>>>(hin, Wl, feat16, NN, CDIM, CDIM,
                                               (long)CDIM * CDIM, (long)NN * CDIM, nullptr, 0);
        compute_eler<<<dim3(NN / 4), dim3(256), 0, stream>>>(
            feat16, attn_l + (size_t)l * RR * CDIM, attn_r + (size_t)l * RR * CDIM, el, er);
        attn_softmax<<<dim3(NN / 4, RR), dim3(256), 0, stream>>>(
            el, er, row_ptr, csr_src, alpha, inv_s);
        aggregate<<<dim3(NN / 4), dim3(256), 0, stream>>>(
            feat16, alpha, inv_s, row_ptr, csr_src, bias + (size_t)l * RR * CDIM,
            h16, (l != LL - 1) ? 1 : 0);
        hin = h16;
    }
    dim3 gf((NN + TM - 1) / TM, OUTD / TN, 1);
    gemm_bf16<<<gf, dim3(256), 0, stream>>>(h16, fct16, out, NN, CDIM, OUTD,
                                            0, 0, fc_b, 1);
}

// Round 4
// 537.592 us; speedup vs baseline: 2.5139x; 1.0984x over previous
//
#include <hip/hip_runtime.h>
#include <math.h>

#define NN 20000
#define EE 320000
#define RR 3
#define LL 3
#define HH 4
#define DD 64
#define CDIM 256   // H*D == IN
#define OUTD 128
#define NEG 0.2f

typedef float f32x4 __attribute__((ext_vector_type(4)));
typedef short sh8 __attribute__((ext_vector_type(8)));

__device__ __forceinline__ ushort f2bf(float f) {
    union { float f; uint u; } v; v.f = f;
    uint r = (v.u + 0x7FFF + ((v.u >> 16) & 1)) >> 16;   // RNE
    return (ushort)r;
}
__device__ __forceinline__ float bf2f(ushort u) {
    union { uint u; float f; } v; v.u = ((uint)u) << 16;
    return v.f;
}
__device__ __forceinline__ float bflo(uint p) { return bf2f((ushort)(p & 0xffff)); }
__device__ __forceinline__ float bfhi(uint p) { return bf2f((ushort)(p >> 16)); }

// ---------------- CSR build ----------------

__global__ void zero_ints(int* p, int n) {
    int i = blockIdx.x * blockDim.x + threadIdx.x;
    if (i < n) p[i] = 0;
}

__global__ void count_deg(const int* __restrict__ edge_dst, int* __restrict__ deg) {
    int i = blockIdx.x * blockDim.x + threadIdx.x;
    if (i >= RR * EE) return;
    int r = i / EE;
    atomicAdd(&deg[r * NN + edge_dst[i]], 1);
}

__global__ void scan_kernel(const int* __restrict__ deg, int* __restrict__ row_ptr) {
    int r = blockIdx.x;
    const int* d = deg + r * NN;
    int* rp = row_ptr + r * (NN + 1);
    __shared__ int buf[1024];
    __shared__ int carry_s;
    if (threadIdx.x == 0) { carry_s = 0; rp[0] = 0; }
    __syncthreads();
    for (int base = 0; base < NN; base += 1024) {
        int i = base + threadIdx.x;
        int v = (i < NN) ? d[i] : 0;
        buf[threadIdx.x] = v;
        __syncthreads();
        for (int off = 1; off < 1024; off <<= 1) {
            int t = (threadIdx.x >= off) ? buf[threadIdx.x - off] : 0;
            __syncthreads();
            buf[threadIdx.x] += t;
            __syncthreads();
        }
        int incl = carry_s + buf[threadIdx.x];
        if (i < NN) rp[i + 1] = incl;
        __syncthreads();
        if (threadIdx.x == 1023) carry_s = carry_s + buf[1023];
        __syncthreads();
    }
}

__global__ void fill_csr(const int* __restrict__ edge_src, const int* __restrict__ edge_dst,
                         const int* __restrict__ row_ptr, int* __restrict__ fill,
                         int* __restrict__ csr_src) {
    int i = blockIdx.x * blockDim.x + threadIdx.x;
    if (i >= RR * EE) return;
    int r = i / EE;
    int dst = edge_dst[i];
    int pos = atomicAdd(&fill[r * NN + dst], 1);
    csr_src[r * EE + row_ptr[r * (NN + 1) + dst] + pos] = edge_src[i];
}

// ---------------- dtype prep ----------------

__global__ void cvt_bf16x4(const float* __restrict__ in, ushort* __restrict__ out, int n4) {
    int i = blockIdx.x * blockDim.x + threadIdx.x;
    if (i >= n4) return;
    float4 v = *(const float4*)(in + (size_t)i * 4);
    ushort4 o;
    o.x = f2bf(v.x); o.y = f2bf(v.y); o.z = f2bf(v.z); o.w = f2bf(v.w);
    *(ushort4*)(out + (size_t)i * 4) = o;
}

// transpose [K][N] fp32 -> [N][K] bf16, one matrix per blockIdx.z
__global__ void prep_Wt(const float* __restrict__ W, ushort* __restrict__ Wt, int K, int N) {
    __shared__ float tile[32][33];
    int kb = blockIdx.x * 32, nb = blockIdx.y * 32;
    size_t base = (size_t)blockIdx.z * K * N;
    for (int yy = threadIdx.y; yy < 32; yy += 8)
        tile[yy][threadIdx.x] = W[base + (size_t)(kb + yy) * N + nb + threadIdx.x];
    __syncthreads();
    for (int yy = threadIdx.y; yy < 32; yy += 8)
        Wt[base + (size_t)(nb + yy) * K + kb + threadIdx.x] = f2bf(tile[threadIdx.x][yy]);
}

// ---------------- bf16 MFMA GEMM (+ fused el/er epilogue) ----------------
// C[M][Ncol] = A[M][K](bf16) @ Bt[Ncol][K](bf16)^T ; 128x128 tile, BK=32,
// 256 threads = 4 waves, each wave 64x64 via 4x4 grid of 16x16x32 MFMA.
// When el_all != null (feature GEMM, Ncol==CDIM): each wave's 64-col span is
// exactly one head, so el/er[(row,head)] is wave-owned: 4 FMA + 16-lane
// shfl-reduce from fp32 acc, no atomics.

#define TM 128
#define TN 128
#define TK 32
#define LP 40   // LDS row pitch in bf16 elems (80 B: 16B-aligned, breaks 2^k bank stride)

__global__ __launch_bounds__(256) void gemm_bf16(
    const ushort* __restrict__ A, const ushort* __restrict__ Bt0, void* __restrict__ C0,
    int M, int K, int Ncol, long strideB, long strideC,
    const float* __restrict__ bias, int out_fp32,
    const float* __restrict__ al_all, const float* __restrict__ ar_all,
    float* __restrict__ el_all, float* __restrict__ er_all) {
    __shared__ alignas(16) ushort As[TM * LP];
    __shared__ alignas(16) ushort Bs[TN * LP];
    const ushort* Bt = Bt0 + (size_t)blockIdx.z * strideB;
    int m0 = blockIdx.x * TM, n0 = blockIdx.y * TN;
    int t = threadIdx.x;
    int wave = t >> 6, lane = t & 63;
    int q = lane >> 4, l16 = lane & 15;
    int wrow = (wave >> 1) * 64, wcol = (wave & 1) * 64;

    f32x4 acc[4][4];
    #pragma unroll
    for (int i = 0; i < 4; i++)
        #pragma unroll
        for (int j = 0; j < 4; j++)
            #pragma unroll
            for (int k = 0; k < 4; k++) acc[i][j][k] = 0.f;

    for (int k0 = 0; k0 < K; k0 += TK) {
        #pragma unroll
        for (int s = 0; s < 2; s++) {
            int qid = t + s * 256;
            int row = qid >> 2, kq = (qid & 3) * 8;
            uint4 v = make_uint4(0, 0, 0, 0);
            int gr = m0 + row;
            if (gr < M) v = *(const uint4*)(A + (size_t)gr * K + k0 + kq);
            *(uint4*)(As + row * LP + kq) = v;
        }
        #pragma unroll
        for (int s = 0; s < 2; s++) {
            int qid = t + s * 256;
            int row = qid >> 2, kq = (qid & 3) * 8;
            uint4 v = *(const uint4*)(Bt + (size_t)(n0 + row) * K + k0 + kq);
            *(uint4*)(Bs + row * LP + kq) = v;
        }
        __syncthreads();
        sh8 af[4], bfr[4];
        #pragma unroll
        for (int i = 0; i < 4; i++)
            af[i] = *(const sh8*)(As + (wrow + i * 16 + l16) * LP + q * 8);
        #pragma unroll
        for (int j = 0; j < 4; j++)
            bfr[j] = *(const sh8*)(Bs + (wcol + j * 16 + l16) * LP + q * 8);
        #pragma unroll
        for (int i = 0; i < 4; i++)
            #pragma unroll
            for (int j = 0; j < 4; j++)
                acc[i][j] = __builtin_amdgcn_mfma_f32_16x16x32_bf16(af[i], bfr[j], acc[i][j], 0, 0, 0);
        __syncthreads();
    }

    // epilogue: C/D layout col=lane&15, row=q*4+reg
    if (out_fp32) {
        float* C = (float*)C0 + (size_t)blockIdx.z * strideC;
        #pragma unroll
        for (int i = 0; i < 4; i++) {
            #pragma unroll
            for (int reg = 0; reg < 4; reg++) {
                int row = m0 + wrow + i * 16 + q * 4 + reg;
                if (row >= M) continue;
                #pragma unroll
                for (int j = 0; j < 4; j++) {
                    int col = n0 + wcol + j * 16 + l16;
                    float v = acc[i][j][reg];
                    if (bias) v += bias[col];
                    C[(size_t)row * Ncol + col] = v;
                }
            }
        }
    } else {
        ushort* C = (ushort*)C0 + (size_t)blockIdx.z * strideC;
        #pragma unroll
        for (int i = 0; i < 4; i++) {
            #pragma unroll
            for (int reg = 0; reg < 4; reg++) {
                int row = m0 + wrow + i * 16 + q * 4 + reg;
                if (row >= M) continue;
                #pragma unroll
                for (int j = 0; j < 4; j++) {
                    int col = n0 + wcol + j * 16 + l16;
                    C[(size_t)row * Ncol + col] = f2bf(acc[i][j][reg]);
                }
            }
        }
    }

    if (el_all) {
        const float* al = al_all + (size_t)blockIdx.z * CDIM;
        const float* ar = ar_all + (size_t)blockIdx.z * CDIM;
        float* elp = el_all + (size_t)blockIdx.z * NN * HH;
        float* erp = er_all + (size_t)blockIdx.z * NN * HH;
        int head = (n0 + wcol) >> 6;
        float alj[4], arj[4];
        #pragma unroll
        for (int j = 0; j < 4; j++) {
            int gcol = n0 + wcol + j * 16 + l16;
            alj[j] = al[gcol];
            arj[j] = ar[gcol];
        }
        #pragma unroll
        for (int i = 0; i < 4; i++) {
            #pragma unroll
            for (int reg = 0; reg < 4; reg++) {
                int row = m0 + wrow + i * 16 + q * 4 + reg;
                float pl = 0.f, pr = 0.f;
                #pragma unroll
                for (int j = 0; j < 4; j++) {
                    pl = fmaf(acc[i][j][reg], alj[j], pl);
                    pr = fmaf(acc[i][j][reg], arj[j], pr);
                }
                #pragma unroll
                for (int m = 1; m < 16; m <<= 1) {
                    pl += __shfl_xor(pl, m, 64);
                    pr += __shfl_xor(pr, m, 64);
                }
                if (l16 == 0 && row < M) {
                    elp[(size_t)row * HH + head] = pl;
                    erp[(size_t)row * HH + head] = pr;
                }
            }
        }
    }
}

// ---------------- fused softmax + aggregation ----------------
// wave per node (4 nodes/block); lane owns 4 channels (one uint2 = 8 B).
// Single pass: accumulate unnormalized p_h = sum a_e * f_e and s_h = sum a_e,
// a_e = exp(leaky(el[src]+er[dst])) computed on the fly (no max-subtract:
// |x| <~ 15 << 88 so fp32 exp cannot overflow; p/s identical to reference).
__global__ __launch_bounds__(256) void aggregate_fused(
    const ushort* __restrict__ feat16, const float* __restrict__ el,
    const float* __restrict__ er, const int* __restrict__ row_ptr,
    const int* __restrict__ csr_src, const float* __restrict__ bias,
    ushort* __restrict__ hout, int relu) {
    int wv = threadIdx.x >> 6, lane = threadIdx.x & 63;
    int node = blockIdx.x * 4 + wv;
    if (node >= NN) return;
    int c0 = lane * 4;
    int h = lane >> 4;
    float t0 = 0.f, t1 = 0.f, t2 = 0.f, t3 = 0.f;
    #pragma unroll
    for (int r = 0; r < RR; r++) {
        const int* rp = row_ptr + r * (NN + 1);
        int beg = rp[node], end = rp[node + 1];
        const ushort* fr = feat16 + (size_t)r * NN * CDIM;
        const float* elr = el + (size_t)r * NN * HH;
        float ern = er[((size_t)r * NN + node) * HH + h];
        const int* cs = csr_src + (size_t)r * EE;
        float p0 = 0.f, p1 = 0.f, p2 = 0.f, p3 = 0.f, ssum = 0.f;
        int e = beg;
        for (; e + 4 <= end; e += 4) {
            int s0 = cs[e], s1 = cs[e + 1], s2 = cs[e + 2], s3 = cs[e + 3];
            float x0 = elr[s0 * HH + h];
            float x1 = elr[s1 * HH + h];
            float x2 = elr[s2 * HH + h];
            float x3 = elr[s3 * HH + h];
            uint2 f0 = *(const uint2*)(fr + (size_t)s0 * CDIM + c0);
            uint2 f1 = *(const uint2*)(fr + (size_t)s1 * CDIM + c0);
            uint2 f2 = *(const uint2*)(fr + (size_t)s2 * CDIM + c0);
            uint2 f3 = *(const uint2*)(fr + (size_t)s3 * CDIM + c0);
            x0 += ern; x1 += ern; x2 += ern; x3 += ern;
            x0 = x0 > 0.f ? x0 : NEG * x0;
            x1 = x1 > 0.f ? x1 : NEG * x1;
            x2 = x2 > 0.f ? x2 : NEG * x2;
            x3 = x3 > 0.f ? x3 : NEG * x3;
            float a0 = __expf(x0), a1 = __expf(x1), a2 = __expf(x2), a3 = __expf(x3);
            ssum += a0 + a1 + a2 + a3;
            p0 = fmaf(a0, bflo(f0.x), p0); p1 = fmaf(a0, bfhi(f0.x), p1);
            p2 = fmaf(a0, bflo(f0.y), p2); p3 = fmaf(a0, bfhi(f0.y), p3);
            p0 = fmaf(a1, bflo(f1.x), p0); p1 = fmaf(a1, bfhi(f1.x), p1);
            p2 = fmaf(a1, bflo(f1.y), p2); p3 = fmaf(a1, bfhi(f1.y), p3);
            p0 = fmaf(a2, bflo(f2.x), p0); p1 = fmaf(a2, bfhi(f2.x), p1);
            p2 = fmaf(a2, bflo(f2.y), p2); p3 = fmaf(a2, bfhi(f2.y), p3);
            p0 = fmaf(a3, bflo(f3.x), p0); p1 = fmaf(a3, bfhi(f3.x), p1);
            p2 = fmaf(a3, bflo(f3.y), p2); p3 = fmaf(a3, bfhi(f3.y), p3);
        }
        for (; e < end; e++) {
            int s = cs[e];
            float x = elr[s * HH + h] + ern;
            x = x > 0.f ? x : NEG * x;
            float a = __expf(x);
            uint2 f = *(const uint2*)(fr + (size_t)s * CDIM + c0);
            ssum += a;
            p0 = fmaf(a, bflo(f.x), p0); p1 = fmaf(a, bfhi(f.x), p1);
            p2 = fmaf(a, bflo(f.y), p2); p3 = fmaf(a, bfhi(f.y), p3);
        }
        float is = (end > beg) ? 1.f / ssum : 0.f;
        t0 += p0 * is + bias[r * CDIM + c0];
        t1 += p1 * is + bias[r * CDIM + c0 + 1];
        t2 += p2 * is + bias[r * CDIM + c0 + 2];
        t3 += p3 * is + bias[r * CDIM + c0 + 3];
    }
    if (relu) {
        t0 = fmaxf(t0, 0.f); t1 = fmaxf(t1, 0.f);
        t2 = fmaxf(t2, 0.f); t3 = fmaxf(t3, 0.f);
    }
    uint2 o;
    o.x = (uint)f2bf(t0) | ((uint)f2bf(t1) << 16);
    o.y = (uint)f2bf(t2) | ((uint)f2bf(t3) << 16);
    *(uint2*)(hout + (size_t)node * CDIM + c0) = o;
}

// ---------------- launcher ----------------

extern "C" void kernel_launch(void* const* d_in, const int* in_sizes, int n_in,
                              void* d_out, int out_size, void* d_ws, size_t ws_size,
                              hipStream_t stream) {
    const float* x        = (const float*)d_in[0];
    const int*   edge_src = (const int*)d_in[1];
    const int*   edge_dst = (const int*)d_in[2];
    const float* W        = (const float*)d_in[3];
    const float* attn_l   = (const float*)d_in[4];
    const float* attn_r   = (const float*)d_in[5];
    const float* bias     = (const float*)d_in[6];
    const float* fc_w     = (const float*)d_in[7];
    const float* fc_b     = (const float*)d_in[8];
    float* out = (float*)d_out;

    char* ws = (char*)d_ws;
    size_t off = 0;
    auto alloc = [&](size_t bytes) {
        void* p = ws + off;
        off = (off + bytes + 255) & ~(size_t)255;
        return p;
    };
    ushort* x16    = (ushort*)alloc((size_t)NN * CDIM * 2);
    ushort* h16    = (ushort*)alloc((size_t)NN * CDIM * 2);
    ushort* feat16 = (ushort*)alloc((size_t)RR * NN * CDIM * 2);
    ushort* Wt16   = (ushort*)alloc((size_t)LL * RR * CDIM * CDIM * 2);
    ushort* fct16  = (ushort*)alloc((size_t)OUTD * CDIM * 2);
    float* el      = (float*)alloc((size_t)RR * NN * HH * 4);
    float* er      = (float*)alloc((size_t)RR * NN * HH * 4);
    int* row_ptr   = (int*)alloc((size_t)RR * (NN + 1) * 4);
    int* csr_src   = (int*)alloc((size_t)RR * EE * 4);
    int* deg       = (int*)alloc((size_t)2 * RR * NN * 4);
    int* fill      = deg + RR * NN;

    // CSR build
    zero_ints<<<dim3((2 * RR * NN + 1023) / 1024), dim3(1024), 0, stream>>>(deg, 2 * RR * NN);
    count_deg<<<dim3((RR * EE + 255) / 256), dim3(256), 0, stream>>>(edge_dst, deg);
    scan_kernel<<<dim3(RR), dim3(1024), 0, stream>>>(deg, row_ptr);
    fill_csr<<<dim3((RR * EE + 255) / 256), dim3(256), 0, stream>>>(edge_src, edge_dst, row_ptr, fill, csr_src);

    // dtype prep
    cvt_bf16x4<<<dim3((NN * CDIM / 4 + 255) / 256), dim3(256), 0, stream>>>(x, x16, NN * CDIM / 4);
    prep_Wt<<<dim3(CDIM / 32, CDIM / 32, LL * RR), dim3(32, 8), 0, stream>>>(W, Wt16, CDIM, CDIM);
    prep_Wt<<<dim3(CDIM / 32, OUTD / 32, 1), dim3(32, 8), 0, stream>>>(fc_w, fct16, CDIM, OUTD);

    const ushort* hin = x16;
    for (int l = 0; l < LL; l++) {
        const ushort* Wl = Wt16 + (size_t)l * RR * CDIM * CDIM;
        dim3 g((NN + TM - 1) / TM, CDIM / TN, RR);
        gemm_bf16<<<g, dim3(256), 0, stream>>>(hin, Wl, feat16, NN, CDIM, CDIM,
                                               (long)CDIM * CDIM, (long)NN * CDIM, nullptr, 0,
                                               attn_l + (size_t)l * RR * CDIM,
                                               attn_r + (size_t)l * RR * CDIM, el, er);
        aggregate_fused<<<dim3(NN / 4), dim3(256), 0, stream>>>(
            feat16, el, er, row_ptr, csr_src, bias + (size_t)l * RR * CDIM,
            h16, (l != LL - 1) ? 1 : 0);
        hin = h16;
    }
    dim3 gf((NN + TM - 1) / TM, OUTD / TN, 1);
    gemm_bf16<<<gf, dim3(256), 0, stream>>>(h16, fct16, out, NN, CDIM, OUTD,
                                            0, 0, fc_b, 1, nullptr, nullptr, nullptr, nullptr);
}

// Round 5
// 535.630 us; speedup vs baseline: 2.5231x; 1.0037x over previous
//
#include <hip/hip_runtime.h>
#include <math.h>

#define NN 20000
#define EE 320000
#define RR 3
#define LL 3
#define HH 4
#define DD 64
#define CDIM 256   // H*D == IN
#define OUTD 128
#define NEG 0.2f

typedef float f32x4 __attribute__((ext_vector_type(4)));
typedef short sh8 __attribute__((ext_vector_type(8)));

__device__ __forceinline__ ushort f2bf(float f) {
    union { float f; uint u; } v; v.f = f;
    uint r = (v.u + 0x7FFF + ((v.u >> 16) & 1)) >> 16;   // RNE
    return (ushort)r;
}
__device__ __forceinline__ float bf2f(ushort u) {
    union { uint u; float f; } v; v.u = ((uint)u) << 16;
    return v.f;
}
__device__ __forceinline__ float bflo(uint p) { return bf2f((ushort)(p & 0xffff)); }
__device__ __forceinline__ float bfhi(uint p) { return bf2f((ushort)(p >> 16)); }

// ---------------- CSR build ----------------

__global__ void zero_ints(int* p, int n) {
    int i = blockIdx.x * blockDim.x + threadIdx.x;
    if (i < n) p[i] = 0;
}

__global__ void count_deg(const int* __restrict__ edge_dst, int* __restrict__ deg) {
    int i = blockIdx.x * blockDim.x + threadIdx.x;
    if (i >= RR * EE) return;
    int r = i / EE;
    atomicAdd(&deg[r * NN + edge_dst[i]], 1);
}

// one block per relation; wave-shfl scan, 3 barriers per 1024-chunk.
__global__ __launch_bounds__(1024) void scan_kernel(
    const int* __restrict__ deg, int* __restrict__ row_ptr) {
    int r = blockIdx.x;
    const int* d = deg + r * NN;
    int* rp = row_ptr + r * (NN + 1);
    __shared__ int wsum[16];
    int lane = threadIdx.x & 63, wv = threadIdx.x >> 6;
    if (threadIdx.x == 0) rp[0] = 0;
    int carry = 0;   // per-thread running total of previous chunks
    for (int base = 0; base < NN; base += 1024) {
        int i = base + threadIdx.x;
        int v = (i < NN) ? d[i] : 0;
        int s = v;
        #pragma unroll
        for (int off = 1; off < 64; off <<= 1) {
            int n = __shfl_up(s, off, 64);
            if (lane >= off) s += n;
        }
        if (lane == 63) wsum[wv] = s;
        __syncthreads();
        if (wv == 0) {
            int ws = (lane < 16) ? wsum[lane] : 0;
            #pragma unroll
            for (int off = 1; off < 16; off <<= 1) {
                int n = __shfl_up(ws, off, 64);
                if (lane >= off) ws += n;
            }
            if (lane < 16) wsum[lane] = ws;
        }
        __syncthreads();
        int incl = carry + (wv ? wsum[wv - 1] : 0) + s;
        if (i < NN) rp[i + 1] = incl;
        carry += wsum[15];
        __syncthreads();
    }
}

__global__ void fill_csr(const int* __restrict__ edge_src, const int* __restrict__ edge_dst,
                         const int* __restrict__ row_ptr, int* __restrict__ fill,
                         int* __restrict__ csr_src) {
    int i = blockIdx.x * blockDim.x + threadIdx.x;
    if (i >= RR * EE) return;
    int r = i / EE;
    int dst = edge_dst[i];
    int pos = atomicAdd(&fill[r * NN + dst], 1);
    csr_src[r * EE + row_ptr[r * (NN + 1) + dst] + pos] = edge_src[i];
}

// ---------------- dtype prep ----------------

__global__ void cvt_bf16x4(const float* __restrict__ in, ushort* __restrict__ out, int n4) {
    int i = blockIdx.x * blockDim.x + threadIdx.x;
    if (i >= n4) return;
    float4 v = *(const float4*)(in + (size_t)i * 4);
    ushort4 o;
    o.x = f2bf(v.x); o.y = f2bf(v.y); o.z = f2bf(v.z); o.w = f2bf(v.w);
    *(ushort4*)(out + (size_t)i * 4) = o;
}

// transpose [K][N] fp32 -> [N][K] bf16, one matrix per blockIdx.z
__global__ void prep_Wt(const float* __restrict__ W, ushort* __restrict__ Wt, int K, int N) {
    __shared__ float tile[32][33];
    int kb = blockIdx.x * 32, nb = blockIdx.y * 32;
    size_t base = (size_t)blockIdx.z * K * N;
    for (int yy = threadIdx.y; yy < 32; yy += 8)
        tile[yy][threadIdx.x] = W[base + (size_t)(kb + yy) * N + nb + threadIdx.x];
    __syncthreads();
    for (int yy = threadIdx.y; yy < 32; yy += 8)
        Wt[base + (size_t)(nb + yy) * K + kb + threadIdx.x] = f2bf(tile[threadIdx.x][yy]);
}

// ---------------- bf16 MFMA GEMM (+ fused el/er epilogue) ----------------

#define TM 128
#define TN 128
#define TK 32
#define LP 40   // LDS row pitch in bf16 elems (80 B: 16B-aligned, breaks 2^k bank stride)

__global__ __launch_bounds__(256) void gemm_bf16(
    const ushort* __restrict__ A, const ushort* __restrict__ Bt0, void* __restrict__ C0,
    int M, int K, int Ncol, long strideB, long strideC,
    const float* __restrict__ bias, int out_fp32,
    const float* __restrict__ al_all, const float* __restrict__ ar_all,
    float* __restrict__ el_all, float* __restrict__ er_all) {
    __shared__ alignas(16) ushort As[TM * LP];
    __shared__ alignas(16) ushort Bs[TN * LP];
    const ushort* Bt = Bt0 + (size_t)blockIdx.z * strideB;
    int m0 = blockIdx.x * TM, n0 = blockIdx.y * TN;
    int t = threadIdx.x;
    int wave = t >> 6, lane = t & 63;
    int q = lane >> 4, l16 = lane & 15;
    int wrow = (wave >> 1) * 64, wcol = (wave & 1) * 64;

    f32x4 acc[4][4];
    #pragma unroll
    for (int i = 0; i < 4; i++)
        #pragma unroll
        for (int j = 0; j < 4; j++)
            #pragma unroll
            for (int k = 0; k < 4; k++) acc[i][j][k] = 0.f;

    for (int k0 = 0; k0 < K; k0 += TK) {
        #pragma unroll
        for (int s = 0; s < 2; s++) {
            int qid = t + s * 256;
            int row = qid >> 2, kq = (qid & 3) * 8;
            uint4 v = make_uint4(0, 0, 0, 0);
            int gr = m0 + row;
            if (gr < M) v = *(const uint4*)(A + (size_t)gr * K + k0 + kq);
            *(uint4*)(As + row * LP + kq) = v;
        }
        #pragma unroll
        for (int s = 0; s < 2; s++) {
            int qid = t + s * 256;
            int row = qid >> 2, kq = (qid & 3) * 8;
            uint4 v = *(const uint4*)(Bt + (size_t)(n0 + row) * K + k0 + kq);
            *(uint4*)(Bs + row * LP + kq) = v;
        }
        __syncthreads();
        sh8 af[4], bfr[4];
        #pragma unroll
        for (int i = 0; i < 4; i++)
            af[i] = *(const sh8*)(As + (wrow + i * 16 + l16) * LP + q * 8);
        #pragma unroll
        for (int j = 0; j < 4; j++)
            bfr[j] = *(const sh8*)(Bs + (wcol + j * 16 + l16) * LP + q * 8);
        #pragma unroll
        for (int i = 0; i < 4; i++)
            #pragma unroll
            for (int j = 0; j < 4; j++)
                acc[i][j] = __builtin_amdgcn_mfma_f32_16x16x32_bf16(af[i], bfr[j], acc[i][j], 0, 0, 0);
        __syncthreads();
    }

    // epilogue: C/D layout col=lane&15, row=q*4+reg
    if (out_fp32) {
        float* C = (float*)C0 + (size_t)blockIdx.z * strideC;
        #pragma unroll
        for (int i = 0; i < 4; i++) {
            #pragma unroll
            for (int reg = 0; reg < 4; reg++) {
                int row = m0 + wrow + i * 16 + q * 4 + reg;
                if (row >= M) continue;
                #pragma unroll
                for (int j = 0; j < 4; j++) {
                    int col = n0 + wcol + j * 16 + l16;
                    float v = acc[i][j][reg];
                    if (bias) v += bias[col];
                    C[(size_t)row * Ncol + col] = v;
                }
            }
        }
    } else {
        ushort* C = (ushort*)C0 + (size_t)blockIdx.z * strideC;
        #pragma unroll
        for (int i = 0; i < 4; i++) {
            #pragma unroll
            for (int reg = 0; reg < 4; reg++) {
                int row = m0 + wrow + i * 16 + q * 4 + reg;
                if (row >= M) continue;
                #pragma unroll
                for (int j = 0; j < 4; j++) {
                    int col = n0 + wcol + j * 16 + l16;
                    C[(size_t)row * Ncol + col] = f2bf(acc[i][j][reg]);
                }
            }
        }
    }

    if (el_all) {
        const float* al = al_all + (size_t)blockIdx.z * CDIM;
        const float* ar = ar_all + (size_t)blockIdx.z * CDIM;
        float* elp = el_all + (size_t)blockIdx.z * NN * HH;
        float* erp = er_all + (size_t)blockIdx.z * NN * HH;
        int head = (n0 + wcol) >> 6;
        float alj[4], arj[4];
        #pragma unroll
        for (int j = 0; j < 4; j++) {
            int gcol = n0 + wcol + j * 16 + l16;
            alj[j] = al[gcol];
            arj[j] = ar[gcol];
        }
        #pragma unroll
        for (int i = 0; i < 4; i++) {
            #pragma unroll
            for (int reg = 0; reg < 4; reg++) {
                int row = m0 + wrow + i * 16 + q * 4 + reg;
                float pl = 0.f, pr = 0.f;
                #pragma unroll
                for (int j = 0; j < 4; j++) {
                    pl = fmaf(acc[i][j][reg], alj[j], pl);
                    pr = fmaf(acc[i][j][reg], arj[j], pr);
                }
                #pragma unroll
                for (int m = 1; m < 16; m <<= 1) {
                    pl += __shfl_xor(pl, m, 64);
                    pr += __shfl_xor(pr, m, 64);
                }
                if (l16 == 0 && row < M) {
                    elp[(size_t)row * HH + head] = pl;
                    erp[(size_t)row * HH + head] = pr;
                }
            }
        }
    }
}

// ---------------- fused softmax + aggregation ----------------
// wave per node (4 nodes/block); lane owns 4 channels (one uint2 = 8 B).
// Exp de-dup: per 4-edge block, lanes 0..15 compute a=exp(leaky(el[src_j]+er[hh]))
// for (edge j=lane&3, head hh=(lane>>2)&3) -- ONE exp chain wave-wide instead of
// four redundant ones -- then 4 shfl broadcasts deliver a0..a3 to each head group.
__global__ __launch_bounds__(256) void aggregate_fused(
    const ushort* __restrict__ feat16, const float* __restrict__ el,
    const float* __restrict__ er, const int* __restrict__ row_ptr,
    const int* __restrict__ csr_src, const float* __restrict__ bias,
    ushort* __restrict__ hout, int relu) {
    int wv = threadIdx.x >> 6, lane = threadIdx.x & 63;
    int node = blockIdx.x * 4 + wv;
    if (node >= NN) return;
    int c0 = lane * 4;
    int h = lane >> 4;
    int jj = lane & 3, hh = (lane >> 2) & 3;   // phase-1 assignment (valid lanes 0..15)
    float t0 = 0.f, t1 = 0.f, t2 = 0.f, t3 = 0.f;
    #pragma unroll
    for (int r = 0; r < RR; r++) {
        const int* rp = row_ptr + r * (NN + 1);
        int beg = rp[node], end = rp[node + 1];
        const ushort* fr = feat16 + (size_t)r * NN * CDIM;
        const float* elr = el + (size_t)r * NN * HH;
        float4 ern4 = *(const float4*)(er + ((size_t)r * NN + node) * HH);
        float ern_own = h == 0 ? ern4.x : h == 1 ? ern4.y : h == 2 ? ern4.z : ern4.w;
        float ern_ph = hh == 0 ? ern4.x : hh == 1 ? ern4.y : hh == 2 ? ern4.z : ern4.w;
        const int* cs = csr_src + (size_t)r * EE;
        float p0 = 0.f, p1 = 0.f, p2 = 0.f, p3 = 0.f, ssum = 0.f;
        int e = beg;
        for (; e + 4 <= end; e += 4) {
            int s0 = cs[e], s1 = cs[e + 1], s2 = cs[e + 2], s3 = cs[e + 3];
            // phase 1: one exp chain wave-wide (lanes >=16 compute ignored dups)
            int sj = jj == 0 ? s0 : jj == 1 ? s1 : jj == 2 ? s2 : s3;
            float xx = elr[sj * HH + hh] + ern_ph;
            xx = xx > 0.f ? xx : NEG * xx;
            float a = __expf(xx);
            // broadcast: a for (head h, edge j) lives on lane h*4+j
            float a0 = __shfl(a, h * 4 + 0, 64);
            float a1 = __shfl(a, h * 4 + 1, 64);
            float a2 = __shfl(a, h * 4 + 2, 64);
            float a3 = __shfl(a, h * 4 + 3, 64);
            uint2 f0 = *(const uint2*)(fr + (size_t)s0 * CDIM + c0);
            uint2 f1 = *(const uint2*)(fr + (size_t)s1 * CDIM + c0);
            uint2 f2 = *(const uint2*)(fr + (size_t)s2 * CDIM + c0);
            uint2 f3 = *(const uint2*)(fr + (size_t)s3 * CDIM + c0);
            ssum += a0 + a1 + a2 + a3;
            p0 = fmaf(a0, bflo(f0.x), p0); p1 = fmaf(a0, bfhi(f0.x), p1);
            p2 = fmaf(a0, bflo(f0.y), p2); p3 = fmaf(a0, bfhi(f0.y), p3);
            p0 = fmaf(a1, bflo(f1.x), p0); p1 = fmaf(a1, bfhi(f1.x), p1);
            p2 = fmaf(a1, bflo(f1.y), p2); p3 = fmaf(a1, bfhi(f1.y), p3);
            p0 = fmaf(a2, bflo(f2.x), p0); p1 = fmaf(a2, bfhi(f2.x), p1);
            p2 = fmaf(a2, bflo(f2.y), p2); p3 = fmaf(a2, bfhi(f2.y), p3);
            p0 = fmaf(a3, bflo(f3.x), p0); p1 = fmaf(a3, bfhi(f3.x), p1);
            p2 = fmaf(a3, bflo(f3.y), p2); p3 = fmaf(a3, bfhi(f3.y), p3);
        }
        for (; e < end; e++) {
            int s = cs[e];
            float x = elr[s * HH + h] + ern_own;
            x = x > 0.f ? x : NEG * x;
            float a = __expf(x);
            uint2 f = *(const uint2*)(fr + (size_t)s * CDIM + c0);
            ssum += a;
            p0 = fmaf(a, bflo(f.x), p0); p1 = fmaf(a, bfhi(f.x), p1);
            p2 = fmaf(a, bflo(f.y), p2); p3 = fmaf(a, bfhi(f.y), p3);
        }
        float is = (end > beg) ? 1.f / ssum : 0.f;
        t0 += p0 * is + bias[r * CDIM + c0];
        t1 += p1 * is + bias[r * CDIM + c0 + 1];
        t2 += p2 * is + bias[r * CDIM + c0 + 2];
        t3 += p3 * is + bias[r * CDIM + c0 + 3];
    }
    if (relu) {
        t0 = fmaxf(t0, 0.f); t1 = fmaxf(t1, 0.f);
        t2 = fmaxf(t2, 0.f); t3 = fmaxf(t3, 0.f);
    }
    uint2 o;
    o.x = (uint)f2bf(t0) | ((uint)f2bf(t1) << 16);
    o.y = (uint)f2bf(t2) | ((uint)f2bf(t3) << 16);
    *(uint2*)(hout + (size_t)node * CDIM + c0) = o;
}

// ---------------- launcher ----------------

extern "C" void kernel_launch(void* const* d_in, const int* in_sizes, int n_in,
                              void* d_out, int out_size, void* d_ws, size_t ws_size,
                              hipStream_t stream) {
    const float* x        = (const float*)d_in[0];
    const int*   edge_src = (const int*)d_in[1];
    const int*   edge_dst = (const int*)d_in[2];
    const float* W        = (const float*)d_in[3];
    const float* attn_l   = (const float*)d_in[4];
    const float* attn_r   = (const float*)d_in[5];
    const float* bias     = (const float*)d_in[6];
    const float* fc_w     = (const float*)d_in[7];
    const float* fc_b     = (const float*)d_in[8];
    float* out = (float*)d_out;

    char* ws = (char*)d_ws;
    size_t off = 0;
    auto alloc = [&](size_t bytes) {
        void* p = ws + off;
        off = (off + bytes + 255) & ~(size_t)255;
        return p;
    };
    ushort* x16    = (ushort*)alloc((size_t)NN * CDIM * 2);
    ushort* h16    = (ushort*)alloc((size_t)NN * CDIM * 2);
    ushort* feat16 = (ushort*)alloc((size_t)RR * NN * CDIM * 2);
    ushort* Wt16   = (ushort*)alloc((size_t)LL * RR * CDIM * CDIM * 2);
    ushort* fct16  = (ushort*)alloc((size_t)OUTD * CDIM * 2);
    float* el      = (float*)alloc((size_t)RR * NN * HH * 4);
    float* er      = (float*)alloc((size_t)RR * NN * HH * 4);
    int* row_ptr   = (int*)alloc((size_t)RR * (NN + 1) * 4);
    int* csr_src   = (int*)alloc((size_t)RR * EE * 4);
    int* deg       = (int*)alloc((size_t)2 * RR * NN * 4);
    int* fill      = deg + RR * NN;

    // CSR build
    zero_ints<<<dim3((2 * RR * NN + 1023) / 1024), dim3(1024), 0, stream>>>(deg, 2 * RR * NN);
    count_deg<<<dim3((RR * EE + 255) / 256), dim3(256), 0, stream>>>(edge_dst, deg);
    scan_kernel<<<dim3(RR), dim3(1024), 0, stream>>>(deg, row_ptr);
    fill_csr<<<dim3((RR * EE + 255) / 256), dim3(256), 0, stream>>>(edge_src, edge_dst, row_ptr, fill, csr_src);

    // dtype prep
    cvt_bf16x4<<<dim3((NN * CDIM / 4 + 255) / 256), dim3(256), 0, stream>>>(x, x16, NN * CDIM / 4);
    prep_Wt<<<dim3(CDIM / 32, CDIM / 32, LL * RR), dim3(32, 8), 0, stream>>>(W, Wt16, CDIM, CDIM);
    prep_Wt<<<dim3(CDIM / 32, OUTD / 32, 1), dim3(32, 8), 0, stream>>>(fc_w, fct16, CDIM, OUTD);

    const ushort* hin = x16;
    for (int l = 0; l < LL; l++) {
        const ushort* Wl = Wt16 + (size_t)l * RR * CDIM * CDIM;
        dim3 g((NN + TM - 1) / TM, CDIM / TN, RR);
        gemm_bf16<<<g, dim3(256), 0, stream>>>(hin, Wl, feat16, NN, CDIM, CDIM,
                                               (long)CDIM * CDIM, (long)NN * CDIM, nullptr, 0,
                                               attn_l + (size_t)l * RR * CDIM,
                                               attn_r + (size_t)l * RR * CDIM, el, er);
        aggregate_fused<<<dim3(NN / 4), dim3(256), 0, stream>>>(
            feat16, el, er, row_ptr, csr_src, bias + (size_t)l * RR * CDIM,
            h16, (l != LL - 1) ? 1 : 0);
        hin = h16;
    }
    dim3 gf((NN + TM - 1) / TM, OUTD / TN, 1);
    gemm_bf16<<<gf, dim3(256), 0, stream>>>(h16, fct16, out, NN, CDIM, OUTD,
                                            0, 0, fc_b, 1, nullptr, nullptr, nullptr, nullptr);
}